// Round 8
// baseline (493.579 us; speedup 1.0000x reference)
//
#include <hip/hip_runtime.h>

#define Bc 32
#define Kc 64
#define Wc 100
#define Hc 150
#define H3c 450
#define KWc 6400
#define ALPHAc 0.2f
#define THRESc 0.0002f

typedef unsigned int u32;
typedef unsigned short u16;
typedef __attribute__((ext_vector_type(8))) short short8;   // 8 bf16
typedef __attribute__((ext_vector_type(4))) float floatx4;  // 4 f32 acc

// ---- ws layout (float offsets), 4.55 MB ----
#define OFF_WX      0u          // 204800  Wx (B,K,W) fp32
#define OFF_CS      204800u     // 2048    causesum (B,K)
#define OFF_GX      206848u     // 921600  gl proj (s,b,g)
#define OFF_HT      1128448u    // 4800    h_t (B,H)
#define OFF_Z       1133248u    // 4800    z (B,H)

__device__ __forceinline__ float us2f(u16 u){ u32 x=((u32)u)<<16; return __uint_as_float(x); }
__device__ __forceinline__ u16 f2us(float f){
  u32 x = __float_as_uint(f);
  u32 r = (x + 0x7fffu + ((x>>16)&1u)) >> 16;   // RNE bf16
  return (u16)r;
}

// LDS-only barrier: __syncthreads() emits s_waitcnt vmcnt(0) lgkmcnt(0) before
// s_barrier, draining the ENTIRE global-memory queue (xp/gx loads + scratch spill
// stores) at HBM latency, twice per GRU step. All in-loop cross-thread data is
// LDS-only, so lgkmcnt(0) suffices; global loads are ordered by register deps.
__device__ __forceinline__ void lds_barrier(){
  __builtin_amdgcn_sched_barrier(0);
  asm volatile("s_waitcnt lgkmcnt(0)" ::: "memory");
  __builtin_amdgcn_s_barrier();
  __builtin_amdgcn_sched_barrier(0);
}

// ---------- Wx = x @ lin_w.T + lin_b ----------
__global__ void wx_kernel(const float* __restrict__ x, const float* __restrict__ lin_w,
                          const float* __restrict__ lin_b, float* __restrict__ ws){
  int o = blockIdx.x*256 + threadIdx.x;
  if (o >= Bc*KWc) return;
  int i = o % Wc;
  int bk = o / Wc;
  const float4* xr = (const float4*)(x + bk*Wc);
  const float4* wr = (const float4*)(lin_w + i*Wc);
  float acc = lin_b[i];
  #pragma unroll
  for (int j=0;j<25;j++){
    float4 xv = xr[j], wv = wr[j];
    acc += xv.x*wv.x + xv.y*wv.y + xv.z*wv.z + xv.w*wv.w;
  }
  ws[OFF_WX + o] = acc;
}

// ---------- attention softmax + thresholded sum (v2: float4, __expf, log-threshold) ----------
__global__ void attn_kernel(const float* __restrict__ y, const float* __restrict__ a,
                            const float* __restrict__ bias, float* __restrict__ ws){
  __shared__ __align__(16) float e_l[KWc];
  __shared__ float red[4];
  int row = blockIdx.x;          // b*64 + k
  int b = row >> 6, k = row & 63;
  int tid = threadIdx.x;
  float a0 = a[0], a1 = a[1];
  float yv = y[row];
  const float4* v4  = (const float4*)(ws + OFF_WX + (size_t)b*KWc);
  const float4* br4 = (const float4*)(bias + (size_t)k*KWc);
  float4* e4 = (float4*)e_l;
  float ay = a0*yv;
  float m = -3.4e38f;
  for (int j=tid; j<KWc/4; j+=256){
    float4 vv = v4[j], bb = br4[j];
    float4 e;
    e.x = ay + a1*vv.x + bb.x; e.x = (e.x>=0.f)?e.x:ALPHAc*e.x;
    e.y = ay + a1*vv.y + bb.y; e.y = (e.y>=0.f)?e.y:ALPHAc*e.y;
    e.z = ay + a1*vv.z + bb.z; e.z = (e.z>=0.f)?e.z:ALPHAc*e.z;
    e.w = ay + a1*vv.w + bb.w; e.w = (e.w>=0.f)?e.w:ALPHAc*e.w;
    e4[j] = e;
    m = fmaxf(m, fmaxf(fmaxf(e.x,e.y), fmaxf(e.z,e.w)));
  }
  for (int o=32;o;o>>=1) m = fmaxf(m, __shfl_down(m, o));
  if ((tid&63)==0) red[tid>>6] = m;
  __syncthreads();
  m = fmaxf(fmaxf(red[0],red[1]), fmaxf(red[2],red[3]));
  __syncthreads();
  float ssum = 0.f;
  for (int j=tid; j<KWc/4; j+=256){
    float4 e = e4[j];
    ssum += __expf(e.x-m) + __expf(e.y-m) + __expf(e.z-m) + __expf(e.w-m);
  }
  for (int o=32;o;o>>=1) ssum += __shfl_down(ssum, o);
  if ((tid&63)==0) red[tid>>6] = ssum;
  __syncthreads();
  float s = red[0]+red[1]+red[2]+red[3];
  // att = exp(e-m)/s >= T  <=>  e >= m + log(T*s)
  float thr = m + logf(THRESc * s);
  float cs = 0.f;
  for (int j=tid; j<KWc/4; j+=256){
    float4 e = e4[j];
    float4 vv = v4[j];
    if (e.x >= thr) cs += vv.x;
    if (e.y >= thr) cs += vv.y;
    if (e.z >= thr) cs += vv.z;
    if (e.w >= thr) cs += vv.w;
  }
  for (int o=32;o;o>>=1) cs += __shfl_down(cs, o);
  if ((tid&63)==0) red[tid>>6] = cs;
  __syncthreads();
  if (tid==0) ws[OFF_CS + row] = red[0]+red[1]+red[2]+red[3];
}

// ---------- gl input projection ----------
__global__ void glproj_kernel(const float* __restrict__ gl_wih, const float* __restrict__ gl_bih,
                              float* __restrict__ ws){
  int o = blockIdx.x*256 + threadIdx.x;
  if (o >= Kc*Bc*H3c) return;
  int g = o % H3c;
  int t = o / H3c;               // s*32 + b
  int b = t & 31, s = t >> 5;
  float cs = ws[OFF_CS + b*Kc + s];
  const float4* xr = (const float4*)(ws + OFF_WX + b*KWc + s*Wc);
  const float4* wr = (const float4*)(gl_wih + g*Wc);
  float acc = gl_bih[g];
  #pragma unroll
  for (int j=0;j<25;j++){
    float4 wv = wr[j], xv = xr[j];
    acc += (xv.x+cs)*wv.x + (xv.y+cs)*wv.y + (xv.z+cs)*wv.z + (xv.w+cs)*wv.w;
  }
  ws[OFF_GX + o] = acc;
}

// ---------- gl recurrent GRU v10: v9 + LDS-only in-loop barriers ----------
__global__ void __launch_bounds__(512,1) glgru4_kernel(
    const float* __restrict__ gl_whh, const float* __restrict__ gl_bhh,
    float* __restrict__ ws){
  __shared__ __align__(16) u16 bF[10*16*40];   // [chunk][n=16(8 used)][k-row stride 40]
  __shared__ float g_l[480*10];                // gate rows x 8 batches, stride 10
  int b0 = blockIdx.x*8;
  int tid = threadIdx.x;
  int w = tid >> 6, lane = tid & 63, quad = lane >> 4, n16 = lane & 15;

  // ---- resident A-fragments (float2 loads: offsets even since Hc=150 even) ----
  short8 whhA[4][5];
  #pragma unroll
  for (int ti=0; ti<4; ti++){
    int tile = w*4 + ti;                 // 0..31 (30,31 dummy)
    int sec = tile/10;                   // 0=r,1=z,2=n
    int sr = (tile - sec*10)*16 + n16;   // row within 160-padded section
    bool rowok = (tile < 30) && (sr < Hc);
    int grow = sec*Hc + sr;
    const float* wr = gl_whh + (size_t)grow*Hc;
    #pragma unroll
    for (int c=0;c<5;c++){
      union { short8 v; u16 u[8]; } t8;
      #pragma unroll
      for (int j2=0;j2<4;j2++){
        int kk2 = c*32 + quad*8 + j2*2;
        float2 wv = (rowok && (kk2+1) < Hc) ? *(const float2*)(wr + kk2) : make_float2(0.f,0.f);
        t8.u[j2*2]   = f2us(wv.x);
        t8.u[j2*2+1] = f2us(wv.y);
      }
      whhA[ti][c] = t8.v;
    }
  }
  // zero B staging (pads stay zero; h0 = 0)
  for (int i=tid; i<10*16*40/2; i+=512) ((u32*)bF)[i] = 0u;

  // ---- per-task state: 1200 tasks, <=3/thread, bl = tau/150, t = tau%150 ----
  float hst[3] = {0.f,0.f,0.f};
  float bh_r[3], bh_z[3], bh_n[3];
  int tT[3], tBL[3];
  #pragma unroll
  for (int q=0;q<3;q++){
    int task = tid + q*512;
    if (task < 1200){
      int bl = task/150, t = task - bl*150;
      tT[q] = t; tBL[q] = bl;
      bh_r[q] = gl_bhh[t];
      bh_z[q] = gl_bhh[Hc+t];
      bh_n[q] = gl_bhh[2*Hc+t];
    } else { tT[q] = 0; tBL[q] = -1; }
  }

  for (int s=0;s<Kc;s++){
    lds_barrier();   // bF ready (LDS-only sync; no vmcnt drain)
    // prefetch gx (issued after barrier -> hidden under MFMA phase)
    float gxr[3], gxz[3], gxn[3];
    const float* gxb = ws + OFF_GX + (size_t)(s*Bc)*H3c;
    #pragma unroll
    for (int q=0;q<3;q++){
      if (tBL[q] >= 0){
        const float* gp = gxb + (size_t)(b0+tBL[q])*H3c;
        int t = tT[q];
        gxr[q] = gp[t]; gxz[q] = gp[Hc+t]; gxn[q] = gp[2*Hc+t];
      }
    }
    // MFMA stage: burst-load all 10 B fragments, single waitcnt, then MFMA run
    const u16* bBase = bF + (size_t)n16*40 + (size_t)quad*8;
    short8 bh[10];
    #pragma unroll
    for (int c=0;c<10;c++) bh[c] = *(const short8*)(bBase + (size_t)c*640);
    floatx4 acc[4] = {{0.f,0.f,0.f,0.f},{0.f,0.f,0.f,0.f},{0.f,0.f,0.f,0.f},{0.f,0.f,0.f,0.f}};
    #pragma unroll
    for (int c=0;c<10;c++){
      int ca = (c<5)? c : (c-5);
      #pragma unroll
      for (int ti=0;ti<4;ti++)
        acc[ti] = __builtin_amdgcn_mfma_f32_16x16x32_bf16(whhA[ti][ca], bh[c], acc[ti], 0,0,0);
    }
    // C -> LDS (C layout: col=lane&15, row=quad*4+reg); only 8 batches used
    if (n16 < 8){
      #pragma unroll
      for (int ti=0;ti<4;ti++){
        int tile = w*4 + ti;
        if (tile < 30){
          int row0 = tile*16 + quad*4;
          float* gp = g_l + row0*10 + n16;
          #pragma unroll
          for (int r=0;r<4;r++) gp[r*10] = acc[ti][r];
        }
      }
    }
    lds_barrier();   // gates ready; bF MFMA reads done
    // gate phase: burst all g_l reads first (ILP across tasks), then compute
    float grv[3], gzv[3], gnv[3];
    #pragma unroll
    for (int q=0;q<3;q++){
      if (tBL[q] >= 0){
        int t = tT[q], bl = tBL[q];
        grv[q] = g_l[t*10+bl];
        gzv[q] = g_l[(160+t)*10+bl];
        gnv[q] = g_l[(320+t)*10+bl];
      }
    }
    #pragma unroll
    for (int q=0;q<3;q++){
      if (tBL[q] >= 0){
        int t = tT[q], bl = tBL[q];
        float a_r = gxr[q] + grv[q] + bh_r[q];
        float a_z = gxz[q] + gzv[q] + bh_z[q];
        float r  = 1.f/(1.f+__expf(-a_r));
        float zz = 1.f/(1.f+__expf(-a_z));
        float nx = gxn[q] + r*(gnv[q] + bh_n[q]);
        nx = fminf(fmaxf(nx,-15.f),15.f);
        float e2 = __expf(2.f*nx);
        float n = (e2-1.f)/(e2+1.f);
        float h = (1.f-zz)*n + zz*hst[q];
        hst[q] = h;
        u16 hi = f2us(h); float hif = us2f(hi); u16 lo = f2us(h - hif);
        bF[(t>>5)*640 + bl*40 + (t&31)] = hi;
        bF[(5+(t>>5))*640 + bl*40 + (t&31)] = lo;
      }
    }
  }
  #pragma unroll
  for (int q=0;q<3;q++){
    if (tBL[q] >= 0)
      ws[OFF_HT + (size_t)(b0+tBL[q])*Hc + tT[q]] = hst[q];
  }
}

// ---------- z = mu + sigma * z_noise ----------
__global__ void z_kernel(const float* __restrict__ z_noise, const float* __restrict__ mu_w,
                         const float* __restrict__ mu_b, const float* __restrict__ std_w,
                         const float* __restrict__ std_b, float* __restrict__ ws){
  int o = blockIdx.x*256 + threadIdx.x;
  if (o >= Bc*Hc) return;
  int t = o % Hc, b = o / Hc;
  const float* h = ws + OFF_HT + b*Hc;
  const float2* mwr = (const float2*)(mu_w + t*Hc);
  const float2* swr = (const float2*)(std_w + t*Hc);
  float mu = mu_b[t], lv = std_b[t];
  for (int j=0;j<Hc/2;j++){
    float2 mw = mwr[j], sw = swr[j];
    float h0 = h[2*j], h1 = h[2*j+1];
    mu += h0*mw.x + h1*mw.y;
    lv += h0*sw.x + h1*sw.y;
  }
  float sg = expf(0.5f*lv);
  ws[OFF_Z + o] = mu + sg*z_noise[o];
}

// ---------- causes v10: v9 (fence-split bursts) + LDS-only in-loop barriers ----------
__global__ void __launch_bounds__(512,1) causes3_kernel(
    const float* __restrict__ net_wih, const float* __restrict__ net_whh,
    const float* __restrict__ net_bih, const float* __restrict__ net_bhh,
    const float* __restrict__ ws, float* __restrict__ out){
  __shared__ __align__(16) u16 bF[14*16*40];   // [chunk][n=16(8 used)][k-row stride 40]
  __shared__ float g_rz[320*10];
  __shared__ float g_nh[160*10];
  __shared__ float g_np[160*10];
  int kk = blockIdx.x & 63, bg = blockIdx.x >> 6, b0 = bg*8;
  int tid = threadIdx.x;
  int w = tid >> 6, lane = tid & 63, quad = lane >> 4, n16 = lane & 15;
  const float* whhk = net_whh + (size_t)kk*H3c*Hc;
  const float* wihk = net_wih + (size_t)kk*H3c*Wc;
  const float* bihk = net_bih + kk*H3c;
  const float* bhhk = net_bhh + kk*H3c;

  short8 whhA[4][5], wihA[4][4];
  #pragma unroll
  for (int ti=0; ti<4; ti++){
    int tile = w*4 + ti;
    int sec = tile/10;
    int sr = (tile - sec*10)*16 + n16;
    bool rowok = (tile < 30) && (sr < Hc);
    int grow = sec*Hc + sr;
    #pragma unroll
    for (int c=0;c<5;c++){
      union { short8 v; u16 u[8]; } t8;
      #pragma unroll
      for (int j=0;j<8;j++){
        int k = c*32 + quad*8 + j;
        float v = (rowok && k < Hc) ? whhk[(size_t)grow*Hc + k] : 0.f;
        t8.u[j] = f2us(v);
      }
      whhA[ti][c] = t8.v;
    }
    #pragma unroll
    for (int c=0;c<4;c++){
      union { short8 v; u16 u[8]; } t8;
      #pragma unroll
      for (int j=0;j<8;j++){
        int k = c*32 + quad*8 + j;
        float v = (rowok && k < Wc) ? wihk[(size_t)grow*Wc + k] : 0.f;
        t8.u[j] = f2us(v);
      }
      wihA[ti][c] = t8.v;
    }
  }

  for (int i=tid; i<14*16*40/2; i+=512) ((u32*)bF)[i] = 0u;

  float hst[3] = {0.f,0.f,0.f};
  float brz_r[3], brz_z[3], bnh_[3], bnp_[3];
  #pragma unroll
  for (int q=0;q<3;q++){
    int task = tid + q*512;
    if (task < 1200){
      int t = task >> 3, bb = task & 7;
      float h = ws[OFF_Z + (b0+bb)*Hc + t];
      hst[q] = h;
      brz_r[q] = bhhk[t]      + bihk[t];
      brz_z[q] = bhhk[Hc+t]   + bihk[Hc+t];
      bnh_[q]  = bhhk[2*Hc+t];
      bnp_[q]  = bihk[2*Hc+t];
      u16 hi = f2us(h); float hif = us2f(hi); u16 lo = f2us(h - hif);
      bF[(t>>5)*640 + bb*40 + (t&31)] = hi;
      bF[(5+(t>>5))*640 + bb*40 + (t&31)] = lo;
    }
  }
  for (int it=tid; it<800; it+=512){
    int bb = it/100, i = it - bb*100;
    float xv = ws[OFF_WX + (b0+bb)*KWc + i];
    bF[(10+(i>>5))*640 + bb*40 + (i&31)] = f2us(xv);
  }

  // x-staging indices (fixed per thread): item0 = tid (<800 always), item1 = tid+512 (<800 iff tid<288)
  int bb0 = tid/100, i0 = tid - bb0*100;
  int it1 = tid + 512;
  int bb1 = it1/100, i1 = it1 - bb1*100;
  bool v1ok = (it1 < 800);

  const bool isN = (w >= 5);
  for (int s=0;s<Kc;s++){
    // hoisted global loads for next step's x staging (pure reads of ws, no deps)
    float xp0 = 0.f, xp1 = 0.f;
    if (s < Kc-1){
      xp0 = ws[OFF_WX + (size_t)(b0+bb0)*KWc + (s+1)*Wc + i0];
      if (v1ok) xp1 = ws[OFF_WX + (size_t)(b0+bb1)*KWc + (s+1)*Wc + i1];
    }
    lds_barrier();   // h+x staging ready (LDS-only sync; no vmcnt drain)
    const u16* bBase = bF + (size_t)n16*40 + (size_t)quad*8;
    // ---- phase A: wih . x ----
    short8 bx[4];
    #pragma unroll
    for (int c=0;c<4;c++) bx[c] = *(const short8*)(bBase + (size_t)(10+c)*640);
    floatx4 acc[4] = {{0.f,0.f,0.f,0.f},{0.f,0.f,0.f,0.f},{0.f,0.f,0.f,0.f},{0.f,0.f,0.f,0.f}};
    #pragma unroll
    for (int ca=0;ca<4;ca++){
      #pragma unroll
      for (int ti=0;ti<4;ti++)
        acc[ti] = __builtin_amdgcn_mfma_f32_16x16x32_bf16(wihA[ti][ca], bx[ca], acc[ti], 0,0,0);
    }
    // fence: keep bh loads AFTER phase A (prevents 40-reg hoist through phase A)
    __builtin_amdgcn_sched_barrier(0);
    // first half of h fragments (hi)
    short8 bh0[5];
    #pragma unroll
    for (int c=0;c<5;c++) bh0[c] = *(const short8*)(bBase + (size_t)c*640);
    // n-waves: dump P-part, reset acc (overlaps bh0 latency)
    if (isN){
      if (n16 < 8){
        #pragma unroll
        for (int ti=0;ti<4;ti++){
          int tile = w*4 + ti;
          if (tile < 30){
            int srb = (tile - 20)*16 + quad*4;
            float* gq = g_np + srb*10 + n16;
            #pragma unroll
            for (int r=0;r<4;r++) gq[r*10] = acc[ti][r];
          }
        }
      }
      #pragma unroll
      for (int ti=0;ti<4;ti++) acc[ti] = (floatx4){0.f,0.f,0.f,0.f};
    }
    // ---- phase B-hi: whh . h_hi ----
    #pragma unroll
    for (int c=0;c<5;c++){
      #pragma unroll
      for (int ti=0;ti<4;ti++)
        acc[ti] = __builtin_amdgcn_mfma_f32_16x16x32_bf16(whhA[ti][c], bh0[c], acc[ti], 0,0,0);
    }
    // fence: keep bh1 loads AFTER phase B-hi (caps live B regs at 5 fragments)
    __builtin_amdgcn_sched_barrier(0);
    short8 bh1[5];
    #pragma unroll
    for (int c=0;c<5;c++) bh1[c] = *(const short8*)(bBase + (size_t)(5+c)*640);
    // ---- phase B-lo: whh . h_lo ----
    #pragma unroll
    for (int c=0;c<5;c++){
      #pragma unroll
      for (int ti=0;ti<4;ti++)
        acc[ti] = __builtin_amdgcn_mfma_f32_16x16x32_bf16(whhA[ti][c], bh1[c], acc[ti], 0,0,0);
    }
    if (n16 < 8){
      #pragma unroll
      for (int ti=0;ti<4;ti++){
        int tile = w*4 + ti;
        if (tile < 30){
          int sec = tile/10;
          int srb = (tile - sec*10)*16 + quad*4;
          if (sec < 2){
            float* gp = g_rz + (sec*160 + srb)*10 + n16;
            #pragma unroll
            for (int r=0;r<4;r++) gp[r*10] = acc[ti][r];
          } else {
            float* gh = g_nh + srb*10 + n16;
            #pragma unroll
            for (int r=0;r<4;r++) gh[r*10] = acc[ti][r];
          }
        }
      }
    }
    lds_barrier();   // gates ready; bF MFMA reads done
    #pragma unroll
    for (int q=0;q<3;q++){
      int task = tid + q*512;
      if (task < 1200){
        int t = task >> 3, bb = task & 7;
        float a_r = g_rz[t*10+bb] + brz_r[q];
        float a_z = g_rz[(160+t)*10+bb] + brz_z[q];
        float r  = 1.f/(1.f+__expf(-a_r));
        float zz = 1.f/(1.f+__expf(-a_z));
        float nx = (g_np[t*10+bb] + bnp_[q]) + r*(g_nh[t*10+bb] + bnh_[q]);
        nx = fminf(fmaxf(nx,-15.f),15.f);
        float e2 = __expf(2.f*nx);
        float n = (e2-1.f)/(e2+1.f);
        float h = (1.f-zz)*n + zz*hst[q];
        hst[q] = h;
        u16 hi = f2us(h); float hif = us2f(hi); u16 lo = f2us(h - hif);
        bF[(t>>5)*640 + bb*40 + (t&31)] = hi;
        bF[(5+(t>>5))*640 + bb*40 + (t&31)] = lo;
      }
    }
    if (s < Kc-1){
      bF[(10+(i0>>5))*640 + bb0*40 + (i0&31)] = f2us(xp0);
      if (v1ok) bF[(10+(i1>>5))*640 + bb1*40 + (i1&31)] = f2us(xp1);
    }
  }
  #pragma unroll
  for (int q=0;q<3;q++){
    int task = tid + q*512;
    if (task < 1200){
      int t = task >> 3, bb = task & 7;
      out[((size_t)(b0+bb)*Kc + kk)*Hc + t] = hst[q];
    }
  }
}

extern "C" void kernel_launch(void* const* d_in, const int* in_sizes, int n_in,
                              void* d_out, int out_size, void* d_ws, size_t ws_size,
                              hipStream_t stream){
  const float* x        = (const float*)d_in[0];
  const float* y        = (const float*)d_in[1];
  const float* z_noise  = (const float*)d_in[2];
  const float* lin_w    = (const float*)d_in[3];
  const float* lin_b    = (const float*)d_in[4];
  const float* a        = (const float*)d_in[5];
  const float* bias     = (const float*)d_in[6];
  const float* gl_wih   = (const float*)d_in[7];
  const float* gl_whh   = (const float*)d_in[8];
  const float* gl_bih   = (const float*)d_in[9];
  const float* gl_bhh   = (const float*)d_in[10];
  const float* mu_w     = (const float*)d_in[11];
  const float* mu_b     = (const float*)d_in[12];
  const float* std_w    = (const float*)d_in[13];
  const float* std_b    = (const float*)d_in[14];
  const float* net_wih  = (const float*)d_in[15];
  const float* net_whh  = (const float*)d_in[16];
  const float* net_bih  = (const float*)d_in[17];
  const float* net_bhh  = (const float*)d_in[18];
  float* ws = (float*)d_ws;
  float* out = (float*)d_out;

  wx_kernel<<<(Bc*KWc+255)/256, 256, 0, stream>>>(x, lin_w, lin_b, ws);
  attn_kernel<<<Bc*Kc, 256, 0, stream>>>(y, a, bias, ws);
  glproj_kernel<<<(Kc*Bc*H3c+255)/256, 256, 0, stream>>>(gl_wih, gl_bih, ws);
  glgru4_kernel<<<4, 512, 0, stream>>>(gl_whh, gl_bhh, ws);
  z_kernel<<<(Bc*Hc+255)/256, 256, 0, stream>>>(z_noise, mu_w, mu_b, std_w, std_b, ws);
  causes3_kernel<<<Kc*4, 512, 0, stream>>>(net_wih, net_whh, net_bih, net_bhh, ws, out);
}

// Round 9
// 487.808 us; speedup vs baseline: 1.0118x; 1.0118x over previous
//
#include <hip/hip_runtime.h>

#define Bc 32
#define Kc 64
#define Wc 100
#define Hc 150
#define H3c 450
#define KWc 6400
#define ALPHAc 0.2f
#define THRESc 0.0002f

typedef unsigned int u32;
typedef unsigned short u16;
typedef __attribute__((ext_vector_type(8))) short short8;   // 8 bf16
typedef __attribute__((ext_vector_type(4))) float floatx4;  // 4 f32 acc

// ---- ws layout (float offsets), 4.55 MB ----
#define OFF_WX      0u          // 204800  Wx (B,K,W) fp32
#define OFF_CS      204800u     // 2048    causesum (B,K)
#define OFF_GX      206848u     // 921600  gl proj (s,b,g)
#define OFF_HT      1128448u    // 4800    h_t (B,H)
#define OFF_Z       1133248u    // 4800    z (B,H)

__device__ __forceinline__ float us2f(u16 u){ u32 x=((u32)u)<<16; return __uint_as_float(x); }
__device__ __forceinline__ u16 f2us(float f){
  u32 x = __float_as_uint(f);
  u32 r = (x + 0x7fffu + ((x>>16)&1u)) >> 16;   // RNE bf16
  return (u16)r;
}

// LDS-only barrier (kept from v10; neutral but semantically tighter than __syncthreads)
__device__ __forceinline__ void lds_barrier(){
  __builtin_amdgcn_sched_barrier(0);
  asm volatile("s_waitcnt lgkmcnt(0)" ::: "memory");
  __builtin_amdgcn_s_barrier();
  __builtin_amdgcn_sched_barrier(0);
}

// ---------- Wx = x @ lin_w.T + lin_b ----------
__global__ void wx_kernel(const float* __restrict__ x, const float* __restrict__ lin_w,
                          const float* __restrict__ lin_b, float* __restrict__ ws){
  int o = blockIdx.x*256 + threadIdx.x;
  if (o >= Bc*KWc) return;
  int i = o % Wc;
  int bk = o / Wc;
  const float4* xr = (const float4*)(x + bk*Wc);
  const float4* wr = (const float4*)(lin_w + i*Wc);
  float acc = lin_b[i];
  #pragma unroll
  for (int j=0;j<25;j++){
    float4 xv = xr[j], wv = wr[j];
    acc += xv.x*wv.x + xv.y*wv.y + xv.z*wv.z + xv.w*wv.w;
  }
  ws[OFF_WX + o] = acc;
}

// ---------- attention softmax + thresholded sum (v2: float4, __expf, log-threshold) ----------
__global__ void attn_kernel(const float* __restrict__ y, const float* __restrict__ a,
                            const float* __restrict__ bias, float* __restrict__ ws){
  __shared__ __align__(16) float e_l[KWc];
  __shared__ float red[4];
  int row = blockIdx.x;          // b*64 + k
  int b = row >> 6, k = row & 63;
  int tid = threadIdx.x;
  float a0 = a[0], a1 = a[1];
  float yv = y[row];
  const float4* v4  = (const float4*)(ws + OFF_WX + (size_t)b*KWc);
  const float4* br4 = (const float4*)(bias + (size_t)k*KWc);
  float4* e4 = (float4*)e_l;
  float ay = a0*yv;
  float m = -3.4e38f;
  for (int j=tid; j<KWc/4; j+=256){
    float4 vv = v4[j], bb = br4[j];
    float4 e;
    e.x = ay + a1*vv.x + bb.x; e.x = (e.x>=0.f)?e.x:ALPHAc*e.x;
    e.y = ay + a1*vv.y + bb.y; e.y = (e.y>=0.f)?e.y:ALPHAc*e.y;
    e.z = ay + a1*vv.z + bb.z; e.z = (e.z>=0.f)?e.z:ALPHAc*e.z;
    e.w = ay + a1*vv.w + bb.w; e.w = (e.w>=0.f)?e.w:ALPHAc*e.w;
    e4[j] = e;
    m = fmaxf(m, fmaxf(fmaxf(e.x,e.y), fmaxf(e.z,e.w)));
  }
  for (int o=32;o;o>>=1) m = fmaxf(m, __shfl_down(m, o));
  if ((tid&63)==0) red[tid>>6] = m;
  __syncthreads();
  m = fmaxf(fmaxf(red[0],red[1]), fmaxf(red[2],red[3]));
  __syncthreads();
  float ssum = 0.f;
  for (int j=tid; j<KWc/4; j+=256){
    float4 e = e4[j];
    ssum += __expf(e.x-m) + __expf(e.y-m) + __expf(e.z-m) + __expf(e.w-m);
  }
  for (int o=32;o;o>>=1) ssum += __shfl_down(ssum, o);
  if ((tid&63)==0) red[tid>>6] = ssum;
  __syncthreads();
  float s = red[0]+red[1]+red[2]+red[3];
  // att = exp(e-m)/s >= T  <=>  e >= m + log(T*s)
  float thr = m + logf(THRESc * s);
  float cs = 0.f;
  for (int j=tid; j<KWc/4; j+=256){
    float4 e = e4[j];
    float4 vv = v4[j];
    if (e.x >= thr) cs += vv.x;
    if (e.y >= thr) cs += vv.y;
    if (e.z >= thr) cs += vv.z;
    if (e.w >= thr) cs += vv.w;
  }
  for (int o=32;o;o>>=1) cs += __shfl_down(cs, o);
  if ((tid&63)==0) red[tid>>6] = cs;
  __syncthreads();
  if (tid==0) ws[OFF_CS + row] = red[0]+red[1]+red[2]+red[3];
}

// ---------- gl input projection ----------
__global__ void glproj_kernel(const float* __restrict__ gl_wih, const float* __restrict__ gl_bih,
                              float* __restrict__ ws){
  int o = blockIdx.x*256 + threadIdx.x;
  if (o >= Kc*Bc*H3c) return;
  int g = o % H3c;
  int t = o / H3c;               // s*32 + b
  int b = t & 31, s = t >> 5;
  float cs = ws[OFF_CS + b*Kc + s];
  const float4* xr = (const float4*)(ws + OFF_WX + b*KWc + s*Wc);
  const float4* wr = (const float4*)(gl_wih + g*Wc);
  float acc = gl_bih[g];
  #pragma unroll
  for (int j=0;j<25;j++){
    float4 wv = wr[j], xv = xr[j];
    acc += (xv.x+cs)*wv.x + (xv.y+cs)*wv.y + (xv.z+cs)*wv.z + (xv.w+cs)*wv.w;
  }
  ws[OFF_GX + o] = acc;
}

// ---------- gl recurrent GRU v11: 1024 threads / 16 waves, 2 tiles/wave ----------
// 4 rounds frozen at ~2 waves/SIMD lockstep (Occupancy 22%): ~45% of cycles idle.
// 16 waves -> 4 waves/SIMD: 4 independent streams hide LDS/exp/barrier latency.
// Per-wave: whhA 40 + bh 40 + acc 8 + state ~25 ~= 113 < 128-reg cap -> no spill.
__global__ void __launch_bounds__(1024,1) glgru4_kernel(
    const float* __restrict__ gl_whh, const float* __restrict__ gl_bhh,
    float* __restrict__ ws){
  __shared__ __align__(16) u16 bF[10*16*40];   // [chunk][n=16(8 used)][k-row stride 40]
  __shared__ float g_l[480*10];                // gate rows x 8 batches, stride 10
  int b0 = blockIdx.x*8;
  int tid = threadIdx.x;
  int w = tid >> 6, lane = tid & 63, quad = lane >> 4, n16 = lane & 15;

  // ---- resident A-fragments: 2 tiles/wave; waves 0..14 real, wave 15 zero-dummy ----
  short8 whhA[2][5];
  #pragma unroll
  for (int ti=0; ti<2; ti++){
    int tile = w*2 + ti;                 // 0..31 (30,31 dummy)
    int sec = tile/10;                   // 0=r,1=z,2=n
    int sr = (tile - sec*10)*16 + n16;   // row within 160-padded section
    bool rowok = (tile < 30) && (sr < Hc);
    int grow = (sec<3 ? sec : 2)*Hc + sr;
    const float* wr = gl_whh + (size_t)grow*Hc;
    #pragma unroll
    for (int c=0;c<5;c++){
      union { short8 v; u16 u[8]; } t8;
      #pragma unroll
      for (int j2=0;j2<4;j2++){
        int kk2 = c*32 + quad*8 + j2*2;
        float2 wv = (rowok && (kk2+1) < Hc) ? *(const float2*)(wr + kk2) : make_float2(0.f,0.f);
        t8.u[j2*2]   = f2us(wv.x);
        t8.u[j2*2+1] = f2us(wv.y);
      }
      whhA[ti][c] = t8.v;
    }
  }
  // zero B staging (pads stay zero; h0 = 0)
  for (int i=tid; i<10*16*40/2; i+=1024) ((u32*)bF)[i] = 0u;

  // ---- per-task state: 1200 tasks, <=2/thread ----
  float hst[2] = {0.f,0.f};
  float bh_r[2], bh_z[2], bh_n[2];
  int tT[2], tBL[2];
  #pragma unroll
  for (int q=0;q<2;q++){
    int task = tid + q*1024;
    if (task < 1200){
      int bl = task/150, t = task - bl*150;
      tT[q] = t; tBL[q] = bl;
      bh_r[q] = gl_bhh[t];
      bh_z[q] = gl_bhh[Hc+t];
      bh_n[q] = gl_bhh[2*Hc+t];
    } else { tT[q] = 0; tBL[q] = -1; }
  }

  for (int s=0;s<Kc;s++){
    lds_barrier();   // bF ready
    // prefetch gx (issued after barrier -> hidden under MFMA phase)
    float gxr[2], gxz[2], gxn[2];
    const float* gxb = ws + OFF_GX + (size_t)(s*Bc)*H3c;
    #pragma unroll
    for (int q=0;q<2;q++){
      if (tBL[q] >= 0){
        const float* gp = gxb + (size_t)(b0+tBL[q])*H3c;
        int t = tT[q];
        gxr[q] = gp[t]; gxz[q] = gp[Hc+t]; gxn[q] = gp[2*Hc+t];
      }
    }
    // MFMA stage: burst-load all 10 B fragments, single waitcnt, then MFMA run
    const u16* bBase = bF + (size_t)n16*40 + (size_t)quad*8;
    short8 bh[10];
    #pragma unroll
    for (int c=0;c<10;c++) bh[c] = *(const short8*)(bBase + (size_t)c*640);
    floatx4 acc[2] = {{0.f,0.f,0.f,0.f},{0.f,0.f,0.f,0.f}};
    #pragma unroll
    for (int c=0;c<10;c++){
      int ca = (c<5)? c : (c-5);
      #pragma unroll
      for (int ti=0;ti<2;ti++)
        acc[ti] = __builtin_amdgcn_mfma_f32_16x16x32_bf16(whhA[ti][ca], bh[c], acc[ti], 0,0,0);
    }
    // C -> LDS (C layout: col=lane&15, row=quad*4+reg); only 8 batches used
    if (n16 < 8){
      #pragma unroll
      for (int ti=0;ti<2;ti++){
        int tile = w*2 + ti;
        if (tile < 30){
          int row0 = tile*16 + quad*4;
          float* gp = g_l + row0*10 + n16;
          #pragma unroll
          for (int r=0;r<4;r++) gp[r*10] = acc[ti][r];
        }
      }
    }
    lds_barrier();   // gates ready; bF MFMA reads done
    #pragma unroll
    for (int q=0;q<2;q++){
      if (tBL[q] >= 0){
        int t = tT[q], bl = tBL[q];
        float a_r = gxr[q] + g_l[t*10+bl] + bh_r[q];
        float a_z = gxz[q] + g_l[(160+t)*10+bl] + bh_z[q];
        float r  = 1.f/(1.f+__expf(-a_r));
        float zz = 1.f/(1.f+__expf(-a_z));
        float nx = gxn[q] + r*(g_l[(320+t)*10+bl] + bh_n[q]);
        nx = fminf(fmaxf(nx,-15.f),15.f);
        float e2 = __expf(2.f*nx);
        float n = (e2-1.f)/(e2+1.f);
        float h = (1.f-zz)*n + zz*hst[q];
        hst[q] = h;
        u16 hi = f2us(h); float hif = us2f(hi); u16 lo = f2us(h - hif);
        bF[(t>>5)*640 + bl*40 + (t&31)] = hi;
        bF[(5+(t>>5))*640 + bl*40 + (t&31)] = lo;
      }
    }
  }
  #pragma unroll
  for (int q=0;q<2;q++){
    if (tBL[q] >= 0)
      ws[OFF_HT + (size_t)(b0+tBL[q])*Hc + tT[q]] = hst[q];
  }
}

// ---------- z = mu + sigma * z_noise ----------
__global__ void z_kernel(const float* __restrict__ z_noise, const float* __restrict__ mu_w,
                         const float* __restrict__ mu_b, const float* __restrict__ std_w,
                         const float* __restrict__ std_b, float* __restrict__ ws){
  int o = blockIdx.x*256 + threadIdx.x;
  if (o >= Bc*Hc) return;
  int t = o % Hc, b = o / Hc;
  const float* h = ws + OFF_HT + b*Hc;
  const float2* mwr = (const float2*)(mu_w + t*Hc);
  const float2* swr = (const float2*)(std_w + t*Hc);
  float mu = mu_b[t], lv = std_b[t];
  for (int j=0;j<Hc/2;j++){
    float2 mw = mwr[j], sw = swr[j];
    float h0 = h[2*j], h1 = h[2*j+1];
    mu += h0*mw.x + h1*mw.y;
    lv += h0*sw.x + h1*sw.y;
  }
  float sg = expf(0.5f*lv);
  ws[OFF_Z + o] = mu + sg*z_noise[o];
}

// ---------- causes v11: 1024 threads / 16 waves, 2 tiles/wave, split bh bursts ----------
// Sec boundaries (tile 10, 20) align with 2-tile waves: isN = (w>=10), no straddle.
// Peak regs ~126 (whhA 40 + wihA 32 + bh0 20 + acc 8 + state/addr) ~= 128 cap.
__global__ void __launch_bounds__(1024,1) causes3_kernel(
    const float* __restrict__ net_wih, const float* __restrict__ net_whh,
    const float* __restrict__ net_bih, const float* __restrict__ net_bhh,
    const float* __restrict__ ws, float* __restrict__ out){
  __shared__ __align__(16) u16 bF[14*16*40];   // [chunk][n=16(8 used)][k-row stride 40]
  __shared__ float g_rz[320*10];
  __shared__ float g_nh[160*10];
  __shared__ float g_np[160*10];
  int kk = blockIdx.x & 63, bg = blockIdx.x >> 6, b0 = bg*8;
  int tid = threadIdx.x;
  int w = tid >> 6, lane = tid & 63, quad = lane >> 4, n16 = lane & 15;
  const float* whhk = net_whh + (size_t)kk*H3c*Hc;
  const float* wihk = net_wih + (size_t)kk*H3c*Wc;
  const float* bihk = net_bih + kk*H3c;
  const float* bhhk = net_bhh + kk*H3c;

  short8 whhA[2][5], wihA[2][4];
  #pragma unroll
  for (int ti=0; ti<2; ti++){
    int tile = w*2 + ti;                 // 0..31 (30,31 dummy)
    int sec = tile/10;
    int sr = (tile - sec*10)*16 + n16;
    bool rowok = (tile < 30) && (sr < Hc);
    int grow = (sec<3 ? sec : 2)*Hc + sr;
    #pragma unroll
    for (int c=0;c<5;c++){
      union { short8 v; u16 u[8]; } t8;
      #pragma unroll
      for (int j=0;j<8;j++){
        int k = c*32 + quad*8 + j;
        float v = (rowok && k < Hc) ? whhk[(size_t)grow*Hc + k] : 0.f;
        t8.u[j] = f2us(v);
      }
      whhA[ti][c] = t8.v;
    }
    #pragma unroll
    for (int c=0;c<4;c++){
      union { short8 v; u16 u[8]; } t8;
      #pragma unroll
      for (int j=0;j<8;j++){
        int k = c*32 + quad*8 + j;
        float v = (rowok && k < Wc) ? wihk[(size_t)grow*Wc + k] : 0.f;
        t8.u[j] = f2us(v);
      }
      wihA[ti][c] = t8.v;
    }
  }

  for (int i=tid; i<14*16*40/2; i+=1024) ((u32*)bF)[i] = 0u;

  float hst[2] = {0.f,0.f};
  float brz_r[2], brz_z[2], bnh_[2], bnp_[2];
  #pragma unroll
  for (int q=0;q<2;q++){
    int task = tid + q*1024;
    if (task < 1200){
      int t = task >> 3, bb = task & 7;
      float h = ws[OFF_Z + (b0+bb)*Hc + t];
      hst[q] = h;
      brz_r[q] = bhhk[t]      + bihk[t];
      brz_z[q] = bhhk[Hc+t]   + bihk[Hc+t];
      bnh_[q]  = bhhk[2*Hc+t];
      bnp_[q]  = bihk[2*Hc+t];
      u16 hi = f2us(h); float hif = us2f(hi); u16 lo = f2us(h - hif);
      bF[(t>>5)*640 + bb*40 + (t&31)] = hi;
      bF[(5+(t>>5))*640 + bb*40 + (t&31)] = lo;
    } else { tT_dummy: ; }
  }
  if (tid < 800){
    int bb = tid/100, i = tid - bb*100;
    float xv = ws[OFF_WX + (b0+bb)*KWc + i];
    bF[(10+(i>>5))*640 + bb*40 + (i&31)] = f2us(xv);
  }

  // x-staging index (single set: 800 <= 1024)
  bool xok = (tid < 800);
  int bb0 = xok ? tid/100 : 0;
  int i0  = tid - bb0*100;

  const bool isN = (w >= 10);   // tiles 20..29 (n-section); 2-tile waves align at 20
  for (int s=0;s<Kc;s++){
    // hoisted global load for next step's x staging (pure read of ws, no deps)
    float xp0 = 0.f;
    if (xok && s < Kc-1)
      xp0 = ws[OFF_WX + (size_t)(b0+bb0)*KWc + (s+1)*Wc + i0];
    lds_barrier();   // h+x staging ready
    const u16* bBase = bF + (size_t)n16*40 + (size_t)quad*8;
    // ---- phase A: wih . x ----
    short8 bx[4];
    #pragma unroll
    for (int c=0;c<4;c++) bx[c] = *(const short8*)(bBase + (size_t)(10+c)*640);
    floatx4 acc[2] = {{0.f,0.f,0.f,0.f},{0.f,0.f,0.f,0.f}};
    #pragma unroll
    for (int ca=0;ca<4;ca++){
      #pragma unroll
      for (int ti=0;ti<2;ti++)
        acc[ti] = __builtin_amdgcn_mfma_f32_16x16x32_bf16(wihA[ti][ca], bx[ca], acc[ti], 0,0,0);
    }
    // fence: keep bh loads AFTER phase A
    __builtin_amdgcn_sched_barrier(0);
    short8 bh0[5];
    #pragma unroll
    for (int c=0;c<5;c++) bh0[c] = *(const short8*)(bBase + (size_t)c*640);
    // n-waves: dump P-part, reset acc (overlaps bh0 latency)
    if (isN){
      if (n16 < 8){
        #pragma unroll
        for (int ti=0;ti<2;ti++){
          int tile = w*2 + ti;
          if (tile < 30){
            int srb = (tile - 20)*16 + quad*4;
            float* gq = g_np + srb*10 + n16;
            #pragma unroll
            for (int r=0;r<4;r++) gq[r*10] = acc[ti][r];
          }
        }
      }
      #pragma unroll
      for (int ti=0;ti<2;ti++) acc[ti] = (floatx4){0.f,0.f,0.f,0.f};
    }
    // ---- phase B-hi: whh . h_hi ----
    #pragma unroll
    for (int c=0;c<5;c++){
      #pragma unroll
      for (int ti=0;ti<2;ti++)
        acc[ti] = __builtin_amdgcn_mfma_f32_16x16x32_bf16(whhA[ti][c], bh0[c], acc[ti], 0,0,0);
    }
    // fence: keep bh1 loads AFTER phase B-hi
    __builtin_amdgcn_sched_barrier(0);
    short8 bh1[5];
    #pragma unroll
    for (int c=0;c<5;c++) bh1[c] = *(const short8*)(bBase + (size_t)(5+c)*640);
    // ---- phase B-lo: whh . h_lo ----
    #pragma unroll
    for (int c=0;c<5;c++){
      #pragma unroll
      for (int ti=0;ti<2;ti++)
        acc[ti] = __builtin_amdgcn_mfma_f32_16x16x32_bf16(whhA[ti][c], bh1[c], acc[ti], 0,0,0);
    }
    if (n16 < 8){
      #pragma unroll
      for (int ti=0;ti<2;ti++){
        int tile = w*2 + ti;
        if (tile < 30){
          int sec = tile/10;
          int srb = (tile - sec*10)*16 + quad*4;
          if (sec < 2){
            float* gp = g_rz + (sec*160 + srb)*10 + n16;
            #pragma unroll
            for (int r=0;r<4;r++) gp[r*10] = acc[ti][r];
          } else {
            float* gh = g_nh + srb*10 + n16;
            #pragma unroll
            for (int r=0;r<4;r++) gh[r*10] = acc[ti][r];
          }
        }
      }
    }
    lds_barrier();   // gates ready; bF MFMA reads done
    #pragma unroll
    for (int q=0;q<2;q++){
      int task = tid + q*1024;
      if (task < 1200){
        int t = task >> 3, bb = task & 7;
        float a_r = g_rz[t*10+bb] + brz_r[q];
        float a_z = g_rz[(160+t)*10+bb] + brz_z[q];
        float r  = 1.f/(1.f+__expf(-a_r));
        float zz = 1.f/(1.f+__expf(-a_z));
        float nx = (g_np[t*10+bb] + bnp_[q]) + r*(g_nh[t*10+bb] + bnh_[q]);
        nx = fminf(fmaxf(nx,-15.f),15.f);
        float e2 = __expf(2.f*nx);
        float n = (e2-1.f)/(e2+1.f);
        float h = (1.f-zz)*n + zz*hst[q];
        hst[q] = h;
        u16 hi = f2us(h); float hif = us2f(hi); u16 lo = f2us(h - hif);
        bF[(t>>5)*640 + bb*40 + (t&31)] = hi;
        bF[(5+(t>>5))*640 + bb*40 + (t&31)] = lo;
      }
    }
    if (xok && s < Kc-1)
      bF[(10+(i0>>5))*640 + bb0*40 + (i0&31)] = f2us(xp0);
  }
  #pragma unroll
  for (int q=0;q<2;q++){
    int task = tid + q*1024;
    if (task < 1200){
      int t = task >> 3, bb = task & 7;
      out[((size_t)(b0+bb)*Kc + kk)*Hc + t] = hst[q];
    }
  }
}

extern "C" void kernel_launch(void* const* d_in, const int* in_sizes, int n_in,
                              void* d_out, int out_size, void* d_ws, size_t ws_size,
                              hipStream_t stream){
  const float* x        = (const float*)d_in[0];
  const float* y        = (const float*)d_in[1];
  const float* z_noise  = (const float*)d_in[2];
  const float* lin_w    = (const float*)d_in[3];
  const float* lin_b    = (const float*)d_in[4];
  const float* a        = (const float*)d_in[5];
  const float* bias     = (const float*)d_in[6];
  const float* gl_wih   = (const float*)d_in[7];
  const float* gl_whh   = (const float*)d_in[8];
  const float* gl_bih   = (const float*)d_in[9];
  const float* gl_bhh   = (const float*)d_in[10];
  const float* mu_w     = (const float*)d_in[11];
  const float* mu_b     = (const float*)d_in[12];
  const float* std_w    = (const float*)d_in[13];
  const float* std_b    = (const float*)d_in[14];
  const float* net_wih  = (const float*)d_in[15];
  const float* net_whh  = (const float*)d_in[16];
  const float* net_bih  = (const float*)d_in[17];
  const float* net_bhh  = (const float*)d_in[18];
  float* ws = (float*)d_ws;
  float* out = (float*)d_out;

  wx_kernel<<<(Bc*KWc+255)/256, 256, 0, stream>>>(x, lin_w, lin_b, ws);
  attn_kernel<<<Bc*Kc, 256, 0, stream>>>(y, a, bias, ws);
  glproj_kernel<<<(Kc*Bc*H3c+255)/256, 256, 0, stream>>>(gl_wih, gl_bih, ws);
  glgru4_kernel<<<4, 1024, 0, stream>>>(gl_whh, gl_bhh, ws);
  z_kernel<<<(Bc*Hc+255)/256, 256, 0, stream>>>(z_noise, mu_w, mu_b, std_w, std_b, ws);
  causes3_kernel<<<Kc*4, 1024, 0, stream>>>(net_wih, net_whh, net_bih, net_bhh, ws, out);
}